// Round 24
// baseline (31.473 us; speedup 1.0000x reference)
//
#include <hip/hip_runtime.h>

#define MAX_SPIKE 100000.0f

constexpr int BATCH  = 128;
constexpr int NIN    = 1024;
constexpr int MOUT   = 512;
constexpr int NSEG   = 16;            // segments == waves per block
constexpr int SEGLEN = NIN / NSEG;    // 64
constexpr int T      = 1024;          // 16 waves
constexpr int CPB    = 128;           // columns per block (2 per lane, +256B apart)
constexpr int CH     = 4;             // chunk = 4 elements

typedef unsigned long long u64;

__device__ __forceinline__ float fastrcp(float x) {
#if __has_builtin(__builtin_amdgcn_rcpf)
    return __builtin_amdgcn_rcpf(x);   // v_rcp_f32, 1 ulp
#else
    float r; asm volatile("v_rcp_f32 %0, %1" : "=v"(r) : "v"(x)); return r;
#endif
}

// ================= fused kernel: in-block sort + two-pass scan =============
// r23 (triple-buffer CH=4) with the SHADOWING BUG fixed: r23's call sites
// named the trailing-xl temporaries `xl`, colliding with SCREEN4's internal
// `float xl = ... : (XL4)` -- macro expansion made the fallback initializer
// self-referential (uninitialized) for each chunk's LAST element, silently
// rejecting accepts that land there. Macro internals now `xv_/xl_`; call
// sites use `xlt`. Pipeline structure unchanged from r23 (A/B/C static
// slots, issue->use ~2 chunks vs ~200-300 cyc gather latency).
__global__ __launch_bounds__(T, 8) void snn_fused_kernel(const float* __restrict__ x,
                                                         const float* __restrict__ w,
                                                         float* __restrict__ out) {
    __shared__ u64 keys[NIN];                        // 8 KB (sort phase)
    __shared__ __align__(16) float xsl[NIN + 8];     // 4.1 KB sorted xs (+sentinel)
    __shared__ __align__(16) int   rol[NIN];         // 4 KB  byte offsets
    __shared__ float4 partsh[NSEG][64];              // 16 KB (pc0,pi0,pc1,pi1)
    __shared__ float  bestsh[NSEG][CPB];             // 8 KB

    const int tid  = threadIdx.x;
    const int b    = blockIdx.x >> 2;
    const int cg   = blockIdx.x & 3;
    const int seg  = tid >> 6;            // wave == segment (uniform work)
    const int lane = tid & 63;
    const unsigned mo4 = (unsigned)(cg * CPB + lane) * 4u;  // col0; col1 = +256B

    // ---------------- phase A: 2-elem/thread hybrid bitonic argsort --------
    // Active: threads 0-511. thread (wv,l) owns i0 = wv*128+l, i1 = i0+64.
    // key = (float_bits<<32)|index: x >= 0 so uint order == float order;
    // index low bits -> distinct keys -> deterministic == stable argsort.
    {
        const bool act = (tid < 512);
        const int  wv  = (tid >> 6) & 7;
        const int  l   = lane;
        const int  i0  = wv * 128 + l;    // bit6 == 0 always
        const int  i1  = i0 + 64;

        u64 e0 = 0, e1 = 0;
        if (act) {
            e0 = ((u64)__float_as_uint(x[b * NIN + i0]) << 32) | (unsigned)i0;
            e1 = ((u64)__float_as_uint(x[b * NIN + i1]) << 32) | (unsigned)i1;
        }

        auto CE_SHFL = [&](u64& e, int idx, int k, int j) {
            u64 p = __shfl_xor(e, j, 64);
            bool takeMin = (((l & j) == 0) == ((idx & k) == 0));
            e = ((p < e) == takeMin) ? p : e;
        };
        auto CE_J64 = [&](int k) {
            bool asc = ((i0 & k) == 0);
            bool sw  = asc ? (e0 > e1) : (e0 < e1);
            if (sw) { u64 t = e0; e0 = e1; e1 = t; }
        };

        if (act) {
            for (int k = 2; k <= 64; k <<= 1)
                for (int j = k >> 1; j >= 1; j >>= 1) { CE_SHFL(e0, i0, k, j); CE_SHFL(e1, i1, k, j); }
            CE_J64(128);
            for (int j = 32; j >= 1; j >>= 1) { CE_SHFL(e0, i0, 128, j); CE_SHFL(e1, i1, 128, j); }
        }

        for (int k = 256; k <= NIN; k <<= 1) {
            if (act) { keys[i0] = e0; keys[i1] = e1; }
            __syncthreads();
            for (int j = k >> 1; j >= 128; j >>= 1) {
                if (act) {
                    int idx  = ((tid & ~(j - 1)) << 1) | (tid & (j - 1));
                    int part = idx | j;
                    u64 a = keys[idx], c = keys[part];
                    bool asc = ((idx & k) == 0);
                    if (asc ? (a > c) : (a < c)) { keys[idx] = c; keys[part] = a; }
                }
                __syncthreads();
            }
            if (act) {
                e0 = keys[i0]; e1 = keys[i1];
                CE_J64(k);
                for (int j = 32; j >= 1; j >>= 1) { CE_SHFL(e0, i0, k, j); CE_SHFL(e1, i1, k, j); }
            }
        }

        if (act) {
            xsl[i0] = __uint_as_float((unsigned)(e0 >> 32));
            xsl[i1] = __uint_as_float((unsigned)(e1 >> 32));
            rol[i0] = (int)(unsigned)(e0 & 0xFFFFFFFFull) * (MOUT * 4);  // byte off
            rol[i1] = (int)(unsigned)(e1 & 0xFFFFFFFFull) * (MOUT * 4);
        }
        if (tid == 0) xsl[NIN] = MAX_SPIKE;
    }
    __syncthreads();

    // ---------------- phase B: two-pass zero-redundancy scan, 2 cols -------
    const char* wb = (const char*)w;
    float XA[CH], XB[CH], XC[CH];
    float A0[CH], A1[CH], B0[CH], B1[CH], C0[CH], C1[CH];

// read xs chunk (1x ds_read_b128) + ro (1x b128) + 8 gathered weight loads
#define RDIS(X, V0, V1, c_) { const int cc_ = (c_); \
    float4 a_ = *(const float4*)&xsl[cc_ * 4]; \
    X[0] = a_.x; X[1] = a_.y; X[2] = a_.z; X[3] = a_.w; \
    int4 r_ = *(const int4*)&rol[cc_ * 4]; \
    V0[0] = *(const float*)(wb + ((unsigned)r_.x + mo4)); \
    V1[0] = *(const float*)(wb + ((unsigned)r_.x + mo4 + 256u)); \
    V0[1] = *(const float*)(wb + ((unsigned)r_.y + mo4)); \
    V1[1] = *(const float*)(wb + ((unsigned)r_.y + mo4 + 256u)); \
    V0[2] = *(const float*)(wb + ((unsigned)r_.z + mo4)); \
    V1[2] = *(const float*)(wb + ((unsigned)r_.z + mo4 + 256u)); \
    V0[3] = *(const float*)(wb + ((unsigned)r_.w + mo4)); \
    V1[3] = *(const float*)(wb + ((unsigned)r_.w + mo4 + 256u)); }

    const int c0 = seg * (SEGLEN / CH);   // seg*16
    const int c1 = c0 + SEGLEN / CH;      // +16

    // ---- pass 1: cheap partials over own segment only (both cols),
    //      triple-buffered (sequential chunk order preserved)
    float pc0 = 0.0f, pi0 = 0.0f, pc1 = 0.0f, pi1 = 0.0f;
#define CHEAP4(X, V0, V1) { _Pragma("unroll") \
    for (int u = 0; u < CH; ++u) { \
        float xv_ = X[u]; \
        float w0_ = V0[u], w1_ = V1[u]; \
        pc0 += w0_; pi0 = fmaf(w0_, xv_, pi0); \
        pc1 += w1_; pi1 = fmaf(w1_, xv_, pi1); } }

    RDIS(XA, A0, A1, c0);
    RDIS(XB, B0, B1, c0 + 1);
    RDIS(XC, C0, C1, c0 + 2);
    for (int c = c0; c < c1; c += 3) {
        CHEAP4(XA, A0, A1);
        if (c + 3 < c1) RDIS(XA, A0, A1, c + 3);
        if (c + 1 < c1) {
            CHEAP4(XB, B0, B1);
            if (c + 4 < c1) RDIS(XB, B0, B1, c + 4);
        }
        if (c + 2 < c1) {
            CHEAP4(XC, C0, C1);
            if (c + 5 < c1) RDIS(XC, C0, C1, c + 5);
        }
    }
#undef CHEAP4

    partsh[seg][lane] = make_float4(pc0, pi0, pc1, pi1);
    __syncthreads();

    // ---- base = ascending sum of earlier segments' partials
    float bc0 = 0.0f, bi0 = 0.0f, bc1 = 0.0f, bi1 = 0.0f;
    for (int t = 0; t < seg; ++t) {
        float4 p = partsh[t][lane];
        bc0 += p.x; bi0 += p.y; bc1 += p.z; bi1 += p.w;
    }

    float best0 = MAX_SPIKE, best1 = MAX_SPIKE;
    {
        const float xn0 = xsl[c0 * 4];               // xs[seg*64] (window bottom)
        const float xn1 = xsl[c1 * 4];               // xs[(seg+1)*64] (top; seg15 -> sentinel)
        const float ec0 = bc0 + pc0, ei0 = bi0 + pi0;
        const float ec1 = bc1 + pc1, ei1 = bi1 + pi1;
        // pre:   wcum < 1 through segment -> no candidate possible.
        // below: base q under window bottom (margin) -> below forever.
        // above: end q over segment-top (margin) -> q stayed above every
        //        window in the segment (monotone while above) -> no accept.
        bool skip0 = (ec0 < 1.0f) ||
                     ((bc0 > 1.0f) && (bi0 < (xn0 * (bc0 - 1.0f)) * (1.0f - 1e-3f))) ||
                     ((ec0 > 1.0f) && (ei0 > (xn1 * (ec0 - 1.0f)) * (1.0f + 1e-3f)));
        bool skip1 = (ec1 < 1.0f) ||
                     ((bc1 > 1.0f) && (bi1 < (xn0 * (bc1 - 1.0f)) * (1.0f - 1e-3f))) ||
                     ((ec1 > 1.0f) && (ei1 > (xn1 * (ec1 - 1.0f)) * (1.0f + 1e-3f)));
        bool skip = (__all((int)(skip0 && skip1)) != 0);

        if (!skip) {
            float wc0 = bc0, wi0 = bi0, wc1 = bc1, wi1 = bi1;
            // Common path: bounds test on wi vs [xv*d, xl*d] (no trans op).
            // Rare branch computes q via v_rcp (1 ulp, validated r12-r22).
            // wc>=1 kept explicitly (kills the xv=0 ^ wi=0 spurious edge).
            // NOTE: internal vars are xv_/xl_ -- call-site arg must never be
            // named `xl` (r23's shadowing bug: self-referential initializer).
#define SCREEN4(X, V0, V1, XL4) { _Pragma("unroll") \
    for (int u = 0; u < CH; ++u) { \
        float xv_ = X[u]; \
        float xl_ = (u < CH - 1) ? X[u + 1] : (XL4); \
        float w0_ = V0[u], w1_ = V1[u]; \
        wc0 += w0_; wi0 = fmaf(w0_, xv_, wi0); \
        wc1 += w1_; wi1 = fmaf(w1_, xv_, wi1); \
        float d0_ = wc0 - 1.0f; \
        float d1_ = wc1 - 1.0f; \
        bool ok0 = (wc0 >= 1.0f) && (wi0 >= xv_ * d0_) && (wi0 <= xl_ * d0_); \
        bool ok1 = (wc1 >= 1.0f) && (wi1 >= xv_ * d1_) && (wi1 <= xl_ * d1_); \
        if (ok0 | ok1) { \
            float q0_ = wi0 * fastrcp(fmaxf(d0_, 1e-10f)); \
            float q1_ = wi1 * fastrcp(fmaxf(d1_, 1e-10f)); \
            best0 = ok0 ? fminf(best0, q0_) : best0; \
            best1 = ok1 ? fminf(best1, q1_) : best1; \
        } } }

            // triple-buffered screen; slot A holds chunks c0, c0+3, ...;
            // chunk c's trailing bound = next chunk's first xs (reg) or the
            // segment-end value from LDS on the final chunk.
            RDIS(XA, A0, A1, c0);
            RDIS(XB, B0, B1, c0 + 1);
            RDIS(XC, C0, C1, c0 + 2);
            for (int c = c0; c < c1; c += 3) {
                {
                    float xlt = (c + 1 < c1) ? XB[0] : xsl[c1 * 4];
                    SCREEN4(XA, A0, A1, xlt);
                }
                if (c + 3 < c1) RDIS(XA, A0, A1, c + 3);
                if (c + 1 < c1) {
                    float xlt = (c + 2 < c1) ? XC[0] : xsl[c1 * 4];
                    SCREEN4(XB, B0, B1, xlt);
                    if (c + 4 < c1) RDIS(XB, B0, B1, c + 4);
                }
                if (c + 2 < c1) {
                    float xlt = (c + 3 < c1) ? XA[0] : xsl[c1 * 4];  // A reloaded above
                    SCREEN4(XC, C0, C1, xlt);
                    if (c + 5 < c1) RDIS(XC, C0, C1, c + 5);
                }
            }
#undef SCREEN4
        }
    }
#undef RDIS

    bestsh[seg][lane]      = best0;
    bestsh[seg][lane + 64] = best1;
    __syncthreads();
    if (tid < CPB) {
        float r = bestsh[0][tid];
        #pragma unroll
        for (int s = 1; s < NSEG; ++s) r = fminf(r, bestsh[s][tid]);
        out[b * MOUT + cg * CPB + tid] = r;
    }
}

extern "C" void kernel_launch(void* const* d_in, const int* in_sizes, int n_in,
                              void* d_out, int out_size, void* d_ws, size_t ws_size,
                              hipStream_t stream) {
    (void)in_sizes; (void)n_in; (void)out_size; (void)d_ws; (void)ws_size;
    const float* x = (const float*)d_in[0];
    const float* w = (const float*)d_in[1];
    float* out = (float*)d_out;

    hipLaunchKernelGGL(snn_fused_kernel, dim3(BATCH * (MOUT / CPB)), dim3(T),
                       0, stream, x, w, out);
}

// Round 25
// 31.184 us; speedup vs baseline: 1.0093x; 1.0093x over previous
//
#include <hip/hip_runtime.h>

#define MAX_SPIKE 100000.0f

constexpr int BATCH  = 128;
constexpr int NIN    = 1024;
constexpr int MOUT   = 512;
constexpr int NSEG   = 16;            // segments == waves per block
constexpr int SEGLEN = NIN / NSEG;    // 64
constexpr int T      = 1024;          // 16 waves
constexpr int CPB    = 128;           // columns per block (2 per lane, +256B apart)
constexpr int CH     = 4;             // chunk = 4 elements (fits 64-VGPR cap)

typedef unsigned long long u64;

__device__ __forceinline__ float fastrcp(float x) {
#if __has_builtin(__builtin_amdgcn_rcpf)
    return __builtin_amdgcn_rcpf(x);   // v_rcp_f32, 1 ulp
#else
    float r; asm volatile("v_rcp_f32 %0, %1" : "=v"(r) : "v"(x)); return r;
#endif
}

// ================= fused kernel: in-block sort + two-pass scan =============
// FINAL (r22 structure, session best 31.0 us; baseline 103.5 -> 3.3x).
// - Phase A: 2-elem/thread hybrid bitonic argsort in LDS (shfl for j<=32,
//   intra-thread j=64, single-barrier LDS pair-exchange j>=128). 4x redundant
//   across col-groups; redundancy is hidden by co-resident blocks.
// - Phase B: two-pass zero-redundancy scan. Pass 1: each of 16 segment-waves
//   cheap-scans ONLY its 64 elements (fmaf cumsum). Barrier. Segment base =
//   reassociated sum of earlier partials (O(1e-6) vs reference; bf16-invisible
//   by the boundary-compensation identity -- validated r12-r24). Pass 2:
//   screen own segment with three provable skips (pre: wcum<1; below: base q
//   under window bottom; above: end q over segment top -- q monotone while
//   above windows), trans-free common path, v_rcp on the rare accept branch.
// Refuted axes (kept out): dwordx2 gather (3x spill/regress), global_load_lds
// DMA, >2-deep register pipelining (compiler sinks), CH=8 (spill), extra
// barrier elimination (neutral), snapshot-through-HBM (L2 thrash).
__global__ __launch_bounds__(T, 8) void snn_fused_kernel(const float* __restrict__ x,
                                                         const float* __restrict__ w,
                                                         float* __restrict__ out) {
    __shared__ u64 keys[NIN];                        // 8 KB (sort phase)
    __shared__ __align__(16) float xsl[NIN + 8];     // 4.1 KB sorted xs (+sentinel)
    __shared__ __align__(16) int   rol[NIN];         // 4 KB  byte offsets
    __shared__ float4 partsh[NSEG][64];              // 16 KB (pc0,pi0,pc1,pi1)
    __shared__ float  bestsh[NSEG][CPB];             // 8 KB

    const int tid  = threadIdx.x;
    const int b    = blockIdx.x >> 2;
    const int cg   = blockIdx.x & 3;
    const int seg  = tid >> 6;            // wave == segment (uniform work)
    const int lane = tid & 63;
    const unsigned mo4 = (unsigned)(cg * CPB + lane) * 4u;  // col0; col1 = +256B

    // ---------------- phase A: 2-elem/thread hybrid bitonic argsort --------
    // Active: threads 0-511. thread (wv,l) owns i0 = wv*128+l, i1 = i0+64.
    // key = (float_bits<<32)|index: x >= 0 so uint order == float order;
    // index low bits -> distinct keys -> deterministic == stable argsort.
    {
        const bool act = (tid < 512);
        const int  wv  = (tid >> 6) & 7;
        const int  l   = lane;
        const int  i0  = wv * 128 + l;    // bit6 == 0 always
        const int  i1  = i0 + 64;

        u64 e0 = 0, e1 = 0;
        if (act) {
            e0 = ((u64)__float_as_uint(x[b * NIN + i0]) << 32) | (unsigned)i0;
            e1 = ((u64)__float_as_uint(x[b * NIN + i1]) << 32) | (unsigned)i1;
        }

        auto CE_SHFL = [&](u64& e, int idx, int k, int j) {
            u64 p = __shfl_xor(e, j, 64);
            bool takeMin = (((l & j) == 0) == ((idx & k) == 0));
            e = ((p < e) == takeMin) ? p : e;
        };
        auto CE_J64 = [&](int k) {
            bool asc = ((i0 & k) == 0);
            bool sw  = asc ? (e0 > e1) : (e0 < e1);
            if (sw) { u64 t = e0; e0 = e1; e1 = t; }
        };

        if (act) {
            for (int k = 2; k <= 64; k <<= 1)
                for (int j = k >> 1; j >= 1; j >>= 1) { CE_SHFL(e0, i0, k, j); CE_SHFL(e1, i1, k, j); }
            CE_J64(128);
            for (int j = 32; j >= 1; j >>= 1) { CE_SHFL(e0, i0, 128, j); CE_SHFL(e1, i1, 128, j); }
        }

        for (int k = 256; k <= NIN; k <<= 1) {
            if (act) { keys[i0] = e0; keys[i1] = e1; }
            __syncthreads();
            for (int j = k >> 1; j >= 128; j >>= 1) {
                if (act) {
                    int idx  = ((tid & ~(j - 1)) << 1) | (tid & (j - 1));
                    int part = idx | j;
                    u64 a = keys[idx], c = keys[part];
                    bool asc = ((idx & k) == 0);
                    if (asc ? (a > c) : (a < c)) { keys[idx] = c; keys[part] = a; }
                }
                __syncthreads();
            }
            if (act) {
                e0 = keys[i0]; e1 = keys[i1];
                CE_J64(k);
                for (int j = 32; j >= 1; j >>= 1) { CE_SHFL(e0, i0, k, j); CE_SHFL(e1, i1, k, j); }
            }
        }

        if (act) {
            xsl[i0] = __uint_as_float((unsigned)(e0 >> 32));
            xsl[i1] = __uint_as_float((unsigned)(e1 >> 32));
            rol[i0] = (int)(unsigned)(e0 & 0xFFFFFFFFull) * (MOUT * 4);  // byte off
            rol[i1] = (int)(unsigned)(e1 & 0xFFFFFFFFull) * (MOUT * 4);
        }
        if (tid == 0) xsl[NIN] = MAX_SPIKE;
    }
    __syncthreads();

    // ---------------- phase B: two-pass zero-redundancy scan, 2 cols -------
    const char* wb = (const char*)w;
    float XA[CH], XB[CH], A0[CH], A1[CH], B0[CH], B1[CH];

// read xs chunk (1x ds_read_b128) + ro (1x b128) + 8 gathered weight loads
#define RDIS(X, V0, V1, c_) { const int cc_ = (c_); \
    float4 a_ = *(const float4*)&xsl[cc_ * 4]; \
    X[0] = a_.x; X[1] = a_.y; X[2] = a_.z; X[3] = a_.w; \
    int4 r_ = *(const int4*)&rol[cc_ * 4]; \
    V0[0] = *(const float*)(wb + ((unsigned)r_.x + mo4)); \
    V1[0] = *(const float*)(wb + ((unsigned)r_.x + mo4 + 256u)); \
    V0[1] = *(const float*)(wb + ((unsigned)r_.y + mo4)); \
    V1[1] = *(const float*)(wb + ((unsigned)r_.y + mo4 + 256u)); \
    V0[2] = *(const float*)(wb + ((unsigned)r_.z + mo4)); \
    V1[2] = *(const float*)(wb + ((unsigned)r_.z + mo4 + 256u)); \
    V0[3] = *(const float*)(wb + ((unsigned)r_.w + mo4)); \
    V1[3] = *(const float*)(wb + ((unsigned)r_.w + mo4 + 256u)); }

    const int c0 = seg * (SEGLEN / CH);   // seg*16
    const int c1 = c0 + SEGLEN / CH;      // +16 (even)

    // ---- pass 1: cheap partials over own segment only (both cols)
    float pc0 = 0.0f, pi0 = 0.0f, pc1 = 0.0f, pi1 = 0.0f;
#define CHEAP4(X, V0, V1) { _Pragma("unroll") \
    for (int u = 0; u < CH; ++u) { \
        float xv_ = X[u]; \
        float w0_ = V0[u], w1_ = V1[u]; \
        pc0 += w0_; pi0 = fmaf(w0_, xv_, pi0); \
        pc1 += w1_; pi1 = fmaf(w1_, xv_, pi1); } }

    RDIS(XA, A0, A1, c0);
    for (int c = c0; c < c1; c += 2) {
        RDIS(XB, B0, B1, c + 1);
        CHEAP4(XA, A0, A1);
        if (c + 2 < c1) RDIS(XA, A0, A1, c + 2);
        CHEAP4(XB, B0, B1);
    }
#undef CHEAP4

    partsh[seg][lane] = make_float4(pc0, pi0, pc1, pi1);
    __syncthreads();

    // ---- base = ascending sum of earlier segments' partials
    float bc0 = 0.0f, bi0 = 0.0f, bc1 = 0.0f, bi1 = 0.0f;
    for (int t = 0; t < seg; ++t) {
        float4 p = partsh[t][lane];
        bc0 += p.x; bi0 += p.y; bc1 += p.z; bi1 += p.w;
    }

    float best0 = MAX_SPIKE, best1 = MAX_SPIKE;
    {
        const float xn0 = xsl[c0 * 4];               // xs[seg*64] (window bottom)
        const float xn1 = xsl[c1 * 4];               // xs[(seg+1)*64] (top; seg15 -> sentinel)
        const float ec0 = bc0 + pc0, ei0 = bi0 + pi0;
        const float ec1 = bc1 + pc1, ei1 = bi1 + pi1;
        // pre:   wcum < 1 through segment -> no candidate possible.
        // below: base q under window bottom (margin) -> below forever.
        // above: end q over segment-top (margin) -> q stayed above every
        //        window in the segment (monotone while above) -> no accept.
        bool skip0 = (ec0 < 1.0f) ||
                     ((bc0 > 1.0f) && (bi0 < (xn0 * (bc0 - 1.0f)) * (1.0f - 1e-3f))) ||
                     ((ec0 > 1.0f) && (ei0 > (xn1 * (ec0 - 1.0f)) * (1.0f + 1e-3f)));
        bool skip1 = (ec1 < 1.0f) ||
                     ((bc1 > 1.0f) && (bi1 < (xn0 * (bc1 - 1.0f)) * (1.0f - 1e-3f))) ||
                     ((ec1 > 1.0f) && (ei1 > (xn1 * (ec1 - 1.0f)) * (1.0f + 1e-3f)));
        bool skip = (__all((int)(skip0 && skip1)) != 0);

        if (!skip) {
            float wc0 = bc0, wi0 = bi0, wc1 = bc1, wi1 = bi1;
            // Common path: bounds test on wi vs [xv*d, xl*d] (no trans op).
            // Rare branch computes q via v_rcp (1 ulp, validated r12-r24).
            // wc>=1 kept explicitly (kills the xv=0 ^ wi=0 spurious edge).
            // NOTE: internal vars xv_/xl_ -- call-site arg must never be
            // named `xl` (r23's shadowing bug: self-referential initializer).
#define SCREEN4(X, V0, V1, XL4) { _Pragma("unroll") \
    for (int u = 0; u < CH; ++u) { \
        float xv_ = X[u]; \
        float xl_ = (u < CH - 1) ? X[u + 1] : (XL4); \
        float w0_ = V0[u], w1_ = V1[u]; \
        wc0 += w0_; wi0 = fmaf(w0_, xv_, wi0); \
        wc1 += w1_; wi1 = fmaf(w1_, xv_, wi1); \
        float d0_ = wc0 - 1.0f; \
        float d1_ = wc1 - 1.0f; \
        bool ok0 = (wc0 >= 1.0f) && (wi0 >= xv_ * d0_) && (wi0 <= xl_ * d0_); \
        bool ok1 = (wc1 >= 1.0f) && (wi1 >= xv_ * d1_) && (wi1 <= xl_ * d1_); \
        if (ok0 | ok1) { \
            float q0_ = wi0 * fastrcp(fmaxf(d0_, 1e-10f)); \
            float q1_ = wi1 * fastrcp(fmaxf(d1_, 1e-10f)); \
            best0 = ok0 ? fminf(best0, q0_) : best0; \
            best1 = ok1 ? fminf(best1, q1_) : best1; \
        } } }

            RDIS(XA, A0, A1, c0);
            for (int c = c0; c < c1; c += 2) {
                RDIS(XB, B0, B1, c + 1);
                SCREEN4(XA, A0, A1, XB[0]);
                const bool more = (c + 2 < c1);
                if (more) RDIS(XA, A0, A1, c + 2);
                float xlt = more ? XA[0] : xsl[(c + 2) * 4];  // sentinel-safe
                SCREEN4(XB, B0, B1, xlt);
            }
#undef SCREEN4
        }
    }
#undef RDIS

    bestsh[seg][lane]      = best0;
    bestsh[seg][lane + 64] = best1;
    __syncthreads();
    if (tid < CPB) {
        float r = bestsh[0][tid];
        #pragma unroll
        for (int s = 1; s < NSEG; ++s) r = fminf(r, bestsh[s][tid]);
        out[b * MOUT + cg * CPB + tid] = r;
    }
}

extern "C" void kernel_launch(void* const* d_in, const int* in_sizes, int n_in,
                              void* d_out, int out_size, void* d_ws, size_t ws_size,
                              hipStream_t stream) {
    (void)in_sizes; (void)n_in; (void)out_size; (void)d_ws; (void)ws_size;
    const float* x = (const float*)d_in[0];
    const float* w = (const float*)d_in[1];
    float* out = (float*)d_out;

    hipLaunchKernelGGL(snn_fused_kernel, dim3(BATCH * (MOUT / CPB)), dim3(T),
                       0, stream, x, w, out);
}